// Round 4
// baseline (144.055 us; speedup 1.0000x reference)
//
#include <hip/hip_runtime.h>
#include <hip/hip_cooperative_groups.h>
namespace cg = cooperative_groups;

#define B_DIM 4
#define C_DIM 256
#define N_DIM 4096   // 64*64
#define INTER 64
#define LDS_PAD 68   // row stride in floats; 272 B, 16B-aligned, breaks pow2 bank stride

// ws float offsets (all written every call before any read; poison-safe)
#define PSEQ_OFF 0                         // B*64            = 256
#define PSX_OFF  256                       // B*64*C          = 65536
#define PSXE_OFF (256 + 65536)             // B*64*C          = 65536

__device__ inline float wave_red_sum(float v) {
    #pragma unroll
    for (int off = 32; off > 0; off >>= 1) v += __shfl_down(v, off, 64);
    return v;
}

// One cooperative kernel. Grid = 256 blocks (blockIdx.x = b*64 + nb), 256 threads.
// Block (b,nb) owns spatial slice n in [64*nb, 64*nb+64) of batch b.
__global__ __launch_bounds__(256) void k_all(
        const float* __restrict__ x,
        const float* __restrict__ Wq, const float* __restrict__ bq,
        const float* __restrict__ Wk, const float* __restrict__ bk,
        const float* __restrict__ Wc, const float* __restrict__ Wv,
        const float* __restrict__ bv, const float* __restrict__ gamma,
        float* __restrict__ ws, float* __restrict__ out)
{
    __shared__ float xt[C_DIM][LDS_PAD];      // 68 KB: x tile, lives the whole kernel
    __shared__ float uqs[C_DIM], uks[C_DIM];  // phase0: uq/uk; phase2 reuse: t1/t2
    __shared__ float sq[4][64], sk[4][64];    // phase1: wave partials; phase2 reuse: Sx/Sxe
    __shared__ float eq_s[64], ek_s[64];
    __shared__ float cqk[2];
    __shared__ float sSeq;

    const int t  = threadIdx.x;
    const int nb = blockIdx.x & 63;
    const int b  = blockIdx.x >> 6;
    const int n0 = nb * 64;
    const int w  = t >> 6, l = t & 63;

    // ---- phase 0: uq[c] = wq^T Wq[:,c]; uk[c] = wk^T Wk[:,c] (redundant/block, L2-hot)
    {
        float uq = 0.f, uk = 0.f;
        #pragma unroll 8
        for (int o = 0; o < INTER; ++o) {
            uq = fmaf(Wc[o],         Wq[o * C_DIM + t], uq);
            uk = fmaf(Wc[INTER + o], Wk[o * C_DIM + t], uk);
        }
        uqs[t] = uq; uks[t] = uk;
        if (t == 0) { float s = 0.f; for (int o = 0; o < INTER; ++o) s = fmaf(Wc[o], bq[o], s); cqk[0] = s; }
        if (t == 1) { float s = 0.f; for (int o = 0; o < INTER; ++o) s = fmaf(Wc[INTER + o], bk[o], s); cqk[1] = s; }
    }

    // ---- stage x tile: 256 c x 64 n, float4 coalesced (x read from HBM exactly once)
    const float4* x4 = (const float4*)x;
    #pragma unroll
    for (int i = 0; i < 16; ++i) {
        const int f = i * 256 + t;
        const int c = f >> 4, q = f & 15;
        float4 v = x4[((size_t)b * C_DIM + c) * (N_DIM / 4) + (n0 >> 2) + q];
        *(float4*)&xt[c][4 * q] = v;
    }
    __syncthreads();

    // ---- phase 1: eq/ek for the block's 64 n (wave w covers channels [64w,64w+64))
    {
        float aq = 0.f, ak = 0.f;
        const int cb = w * 64;
        #pragma unroll 16
        for (int c = 0; c < 64; ++c) {
            float xv = xt[cb + c][l];         // bank = f(l): conflict-free
            aq = fmaf(uqs[cb + c], xv, aq);
            ak = fmaf(uks[cb + c], xv, ak);
        }
        sq[w][l] = aq; sk[w][l] = ak;
    }
    __syncthreads();
    if (w == 0) {
        float tq = sq[0][l] + sq[1][l] + sq[2][l] + sq[3][l] + cqk[0];
        float tk = sk[0][l] + sk[1][l] + sk[2][l] + sk[3][l] + cqk[1];
        eq_s[l] = tq; ek_s[l] = tk;           // ek never leaves LDS
        float se = wave_red_sum(tq);
        if (l == 0) ws[PSEQ_OFF + b * 64 + nb] = se;
    }
    __syncthreads();

    // ---- phase 1b: per-channel partials Sx/Sxe over this block's 64 n (c = t)
    {
        float sx = 0.f, sxe = 0.f;
        const float4* row = (const float4*)&xt[t][0];
        const float4* ev  = (const float4*)&eq_s[0];
        #pragma unroll
        for (int i = 0; i < 16; ++i) {
            float4 xv = row[i];
            float4 e  = ev[i];
            sx += xv.x + xv.y + xv.z + xv.w;
            sxe = fmaf(xv.x, e.x, sxe); sxe = fmaf(xv.y, e.y, sxe);
            sxe = fmaf(xv.z, e.z, sxe); sxe = fmaf(xv.w, e.w, sxe);
        }
        ws[PSX_OFF  + (size_t)(b * 64 + nb) * C_DIM + t] = sx;
        ws[PSXE_OFF + (size_t)(b * 64 + nb) * C_DIM + t] = sxe;
    }

    cg::this_grid().sync();

    // ---- phase 2 (redundant per block, L2 traffic only): totals + Wv matvec
    {
        float sx = 0.f, sxe = 0.f;
        #pragma unroll 8
        for (int j = 0; j < 64; ++j) {        // coalesced across t
            sx  += ws[PSX_OFF  + (size_t)(b * 64 + j) * C_DIM + t];
            sxe += ws[PSXE_OFF + (size_t)(b * 64 + j) * C_DIM + t];
        }
        ((float*)sq)[t] = sx;                 // reuse sq/sk as Sx/Sxe[256]
        ((float*)sk)[t] = sxe;
        if (w == 0) {
            float se = wave_red_sum(ws[PSEQ_OFF + b * 64 + l]);
            if (l == 0) sSeq = se;
        }
    }
    __syncthreads();
    {
        const float* sSx  = (const float*)sq;
        const float* sSxe = (const float*)sk;
        const float4* wr = (const float4*)(Wv + (size_t)t * C_DIM);
        float sv = 0.f, sve = 0.f;
        #pragma unroll 8
        for (int i = 0; i < 64; ++i) {
            float4 w4 = wr[i];
            const int e = 4 * i;
            sv  = fmaf(w4.x, sSx[e],     sv);
            sv  = fmaf(w4.y, sSx[e + 1], sv);
            sv  = fmaf(w4.z, sSx[e + 2], sv);
            sv  = fmaf(w4.w, sSx[e + 3], sv);
            sve = fmaf(w4.x, sSxe[e],     sve);
            sve = fmaf(w4.y, sSxe[e + 1], sve);
            sve = fmaf(w4.z, sSxe[e + 2], sve);
            sve = fmaf(w4.w, sSxe[e + 3], sve);
        }
        const float ginv = gamma[0] / (float)N_DIM;
        uqs[t] = (sv  + (float)N_DIM * bv[t]) * ginv;   // t1[c] = ginv*Sv
        uks[t] = (sve + bv[t] * sSeq) * ginv;           // t2[c] = ginv*Sve
    }
    __syncthreads();

    // ---- phase 3: epilogue from LDS tile: out = t2[c] + t1[c]*ek[m] + x
    {
        float4* o4 = (float4*)out;
        const int q = t & 15;
        const float4 ek4 = *(const float4*)&ek_s[4 * q];
        #pragma unroll
        for (int i = 0; i < 16; ++i) {
            const int c = i * 16 + (t >> 4);
            const float4 xv = *(const float4*)&xt[c][4 * q];
            const float t1 = uqs[c], t2 = uks[c];
            float4 o;
            o.x = fmaf(ek4.x, t1, t2) + xv.x;
            o.y = fmaf(ek4.y, t1, t2) + xv.y;
            o.z = fmaf(ek4.z, t1, t2) + xv.z;
            o.w = fmaf(ek4.w, t1, t2) + xv.w;
            o4[((size_t)b * C_DIM + c) * (N_DIM / 4) + (n0 >> 2) + q] = o;
        }
    }
}

extern "C" void kernel_launch(void* const* d_in, const int* in_sizes, int n_in,
                              void* d_out, int out_size, void* d_ws, size_t ws_size,
                              hipStream_t stream) {
    const float* x     = (const float*)d_in[0];
    const float* Wq    = (const float*)d_in[1];
    const float* bq    = (const float*)d_in[2];
    const float* Wk    = (const float*)d_in[3];
    const float* bk    = (const float*)d_in[4];
    const float* Wc    = (const float*)d_in[5];
    const float* Wv    = (const float*)d_in[6];
    const float* bv    = (const float*)d_in[7];
    const float* gamma = (const float*)d_in[8];
    float* out = (float*)d_out;
    float* ws  = (float*)d_ws;

    void* args[] = { (void*)&x, (void*)&Wq, (void*)&bq, (void*)&Wk, (void*)&bk,
                     (void*)&Wc, (void*)&Wv, (void*)&bv, (void*)&gamma,
                     (void*)&ws, (void*)&out };
    // 256 blocks x 256 threads; 72.7 KB LDS -> 2 blocks/CU possible, 256 <= capacity.
    hipLaunchCooperativeKernel((const void*)k_all, dim3(B_DIM * 64), dim3(256),
                               args, 0, stream);
}

// Round 8
// 103.330 us; speedup vs baseline: 1.3941x; 1.3941x over previous
//
#include <hip/hip_runtime.h>

#define B_DIM 4
#define C_DIM 256
#define N_DIM 4096   // 64*64
#define INTER 64
#define LDS_PAD 68   // row stride (floats): 272 B, 16B-aligned for b128, breaks pow2 stride

// workspace layout (float offsets)
#define EK_OFF   0                         // B*N   = 16384
#define PSEQ_OFF 16384                     // B*64  = 256
#define PSX_OFF  16640                     // B*64*C = 65536
#define PSXE_OFF 82176                     // B*64*C = 65536

__device__ inline float wave_red_sum(float v) {
    #pragma unroll
    for (int off = 32; off > 0; off >>= 1) v += __shfl_down(v, off, 64);
    return v;
}

// K1: block (nb,b) stages x-tile [256c x 64n] in LDS, computes eq/ek for its 64 n,
// writes ek + per-block partials Sx/Sxe/Seq. x read from HBM exactly once here.
__global__ __launch_bounds__(256) void k_fuse(
        const float* __restrict__ x,
        const float* __restrict__ Wq, const float* __restrict__ bq,
        const float* __restrict__ Wk, const float* __restrict__ bk,
        const float* __restrict__ Wc, float* __restrict__ ws) {
    __shared__ float xt[C_DIM][LDS_PAD];   // ~68 KB
    __shared__ float uqs[C_DIM], uks[C_DIM];
    __shared__ float sq[4][64], sk[4][64];
    __shared__ float eq_s[64];
    __shared__ float cqk[2];
    const int t  = threadIdx.x;
    const int nb = blockIdx.x;             // 0..63
    const int b  = blockIdx.y;             // 0..3
    const int n0 = nb * 64;
    const int w  = t >> 6, l = t & 63;

    // issue the x-tile loads FIRST (latency hides under phase 0)
    float4 xv[16];
    const float4* x4 = (const float4*)x;
    #pragma unroll
    for (int i = 0; i < 16; ++i) {
        const int f = i * 256 + t;
        const int c = f >> 4, q = f & 15;
        xv[i] = x4[((size_t)b * C_DIM + c) * (N_DIM / 4) + (n0 >> 2) + q];
    }

    // phase 0: uq[c] = wq^T Wq[:,c]; uk[c] = wk^T Wk[:,c] (L2-hot, redundant per block)
    {
        float uq = 0.f, uk = 0.f;
        #pragma unroll 8
        for (int o = 0; o < INTER; ++o) {
            uq = fmaf(Wc[o],         Wq[o * C_DIM + t], uq);
            uk = fmaf(Wc[INTER + o], Wk[o * C_DIM + t], uk);
        }
        uqs[t] = uq; uks[t] = uk;
        if (t == 0) { float s = 0.f; for (int o = 0; o < INTER; ++o) s = fmaf(Wc[o], bq[o], s); cqk[0] = s; }
        if (t == 1) { float s = 0.f; for (int o = 0; o < INTER; ++o) s = fmaf(Wc[INTER + o], bk[o], s); cqk[1] = s; }
    }

    // commit x-tile to LDS
    #pragma unroll
    for (int i = 0; i < 16; ++i) {
        const int f = i * 256 + t;
        const int c = f >> 4, q = f & 15;
        *(float4*)&xt[c][4 * q] = xv[i];
    }
    __syncthreads();

    // phase 1: eq/ek for the block's 64 n (wave w covers channels [64w,64w+64))
    {
        float aq = 0.f, ak = 0.f;
        const int cb = w * 64;
        #pragma unroll 16
        for (int c = 0; c < 64; ++c) {
            float xvv = xt[cb + c][l];     // bank = f(l): conflict-free
            aq = fmaf(uqs[cb + c], xvv, aq);
            ak = fmaf(uks[cb + c], xvv, ak);
        }
        sq[w][l] = aq; sk[w][l] = ak;
    }
    __syncthreads();
    if (w == 0) {
        float tq = sq[0][l] + sq[1][l] + sq[2][l] + sq[3][l] + cqk[0];
        float tk = sk[0][l] + sk[1][l] + sk[2][l] + sk[3][l] + cqk[1];
        eq_s[l] = tq;
        ws[EK_OFF + b * N_DIM + n0 + l] = tk;
        float se = wave_red_sum(tq);
        if (l == 0) ws[PSEQ_OFF + b * 64 + nb] = se;
    }
    __syncthreads();

    // phase 1b: per-channel partials Sx/Sxe over this block's 64 n (c = t)
    {
        float sx = 0.f, sxe = 0.f;
        const float4* row = (const float4*)&xt[t][0];
        const float4* ev  = (const float4*)&eq_s[0];
        #pragma unroll
        for (int i = 0; i < 16; ++i) {
            float4 a = row[i];
            float4 e = ev[i];
            sx += a.x + a.y + a.z + a.w;
            sxe = fmaf(a.x, e.x, sxe); sxe = fmaf(a.y, e.y, sxe);
            sxe = fmaf(a.z, e.z, sxe); sxe = fmaf(a.w, e.w, sxe);
        }
        ws[PSX_OFF  + (size_t)(b * 64 + nb) * C_DIM + t] = sx;
        ws[PSXE_OFF + (size_t)(b * 64 + nb) * C_DIM + t] = sxe;
    }
}

// K2: block bid -> (b = bid>>6, cg = (bid>>4)&3, ms = bid&15) owns channels
// [64cg,64cg+64) x m in [256ms, 256ms+256) of batch b.
// Prologue (redundant, L2/L3): reduce partials -> Sx/Sxe/Seq, Wv matvec for its 64
// channels -> t1/t2. Epilogue: out = t2[c] + t1[c]*ek[m] + x, from regs staged early.
__global__ __launch_bounds__(256) void k_sv_out(
        const float* __restrict__ x,  const float* __restrict__ Wv,
        const float* __restrict__ bv, const float* __restrict__ gamma,
        const float* __restrict__ ws, float* __restrict__ out) {
    __shared__ float sSx[C_DIM], sSxe[C_DIM];
    __shared__ float t1s[64], t2s[64];
    __shared__ float sSeqS;
    const int t   = threadIdx.x;
    const int bid = blockIdx.x;
    const int b   = bid >> 6;
    const int cg  = (bid >> 4) & 3;
    const int ms  = bid & 15;
    const int w   = t >> 6, l = t & 63;

    // stage this block's x-tile into regs FIRST: iter i -> channel cg*64 + i*4 + w,
    // f4-column ms*64 + l. Each wave-instr reads 64 consecutive float4 = 1 KB.
    float4 xv[16];
    const float4* x4 = (const float4*)x;
    #pragma unroll
    for (int i = 0; i < 16; ++i)
        xv[i] = x4[((size_t)b * C_DIM + cg * 64 + i * 4 + w) * (N_DIM / 4) + ms * 64 + l];
    // ek for this thread's 4 m's (same for all i)
    const float4 ek4 = ((const float4*)(ws + EK_OFF + (size_t)b * N_DIM))[ms * 64 + l];

    // prologue: reduce per-block partials (coalesced across t)
    {
        float sx = 0.f, sxe = 0.f;
        #pragma unroll 8
        for (int j = 0; j < 64; ++j) {
            sx  += ws[PSX_OFF  + (size_t)(b * 64 + j) * C_DIM + t];
            sxe += ws[PSXE_OFF + (size_t)(b * 64 + j) * C_DIM + t];
        }
        sSx[t] = sx; sSxe[t] = sxe;
        if (w == 0) {
            float se = wave_red_sum(ws[PSEQ_OFF + b * 64 + l]);
            if (l == 0) sSeqS = se;
        }
    }
    __syncthreads();

    // Wv matvec for this block's 64 channels; 4 lanes per output dot
    {
        const int cl = t >> 2, s = t & 3;
        const int c  = cg * 64 + cl;
        const float4* wr = (const float4*)(Wv + (size_t)c * C_DIM + 64 * s);
        float sv = 0.f, sve = 0.f;
        #pragma unroll
        for (int i = 0; i < 16; ++i) {
            float4 w4 = wr[i];
            const int e = 64 * s + 4 * i;
            sv  = fmaf(w4.x, sSx[e],     sv);
            sv  = fmaf(w4.y, sSx[e + 1], sv);
            sv  = fmaf(w4.z, sSx[e + 2], sv);
            sv  = fmaf(w4.w, sSx[e + 3], sv);
            sve = fmaf(w4.x, sSxe[e],     sve);
            sve = fmaf(w4.y, sSxe[e + 1], sve);
            sve = fmaf(w4.z, sSxe[e + 2], sve);
            sve = fmaf(w4.w, sSxe[e + 3], sve);
        }
        sv  += __shfl_down(sv, 2, 64);  sv  += __shfl_down(sv, 1, 64);
        sve += __shfl_down(sve, 2, 64); sve += __shfl_down(sve, 1, 64);
        if (s == 0) {
            const float ginv = gamma[0] / (float)N_DIM;
            t1s[cl] = (sv  + (float)N_DIM * bv[c]) * ginv;
            t2s[cl] = (sve + bv[c] * sSeqS) * ginv;
        }
    }
    __syncthreads();

    // epilogue: out = t2[c] + t1[c]*ek[m] + x
    float4* o4 = (float4*)out;
    #pragma unroll
    for (int i = 0; i < 16; ++i) {
        const int cl = i * 4 + w;
        const float t1 = t1s[cl], t2 = t2s[cl];
        float4 o;
        o.x = fmaf(ek4.x, t1, t2) + xv[i].x;
        o.y = fmaf(ek4.y, t1, t2) + xv[i].y;
        o.z = fmaf(ek4.z, t1, t2) + xv[i].z;
        o.w = fmaf(ek4.w, t1, t2) + xv[i].w;
        o4[((size_t)b * C_DIM + cg * 64 + cl) * (N_DIM / 4) + ms * 64 + l] = o;
    }
}

extern "C" void kernel_launch(void* const* d_in, const int* in_sizes, int n_in,
                              void* d_out, int out_size, void* d_ws, size_t ws_size,
                              hipStream_t stream) {
    const float* x     = (const float*)d_in[0];
    const float* Wq    = (const float*)d_in[1];
    const float* bq    = (const float*)d_in[2];
    const float* Wk    = (const float*)d_in[3];
    const float* bk    = (const float*)d_in[4];
    const float* Wc    = (const float*)d_in[5];
    const float* Wv    = (const float*)d_in[6];
    const float* bv    = (const float*)d_in[7];
    const float* gamma = (const float*)d_in[8];
    float* out = (float*)d_out;
    float* ws  = (float*)d_ws;

    dim3 gA(N_DIM / 64, B_DIM);            // 64 x 4 = 256 blocks
    k_fuse<<<gA, 256, 0, stream>>>(x, Wq, bq, Wk, bk, Wc, ws);

    k_sv_out<<<256, 256, 0, stream>>>(x, Wv, bv, gamma, ws, out);
}